// Round 1
// baseline (298.695 us; speedup 1.0000x reference)
//
#include <hip/hip_runtime.h>
#include <math.h>

// WfcNN: B=262144 samples.
//   h1 = tanh(x @ W0 + b0)            (B,128)
//   h2 = tanh(h1 @ W1 + b1)           (B,64)
//   g  = tanh(h2 . Wa[eid] + ba[eid]) (B,32)
//   psi= g . Wb[eid] + bb[eid]        (B,2) ; out = psi / sqrt(|psi|^2+1e-6)
// eid = sum_{i<n} i^2 + l*l + l + m  (30 experts)
//
// Round 1: fp32 baseline. Fused layer2+expert per-d loop so no register array
// needs dynamic indexing (h1[128] static via full unroll; g[32] static).
// W1^T staged in LDS (stride 132 for float4 alignment); reads are
// wave-uniform -> broadcast, conflict-free.

#define THREADS 256

__device__ __forceinline__ float fast_tanh(float v) {
    // tanh(v) = (e^{2v}-1)/(e^{2v}+1); clamp to avoid inf*0
    v = fminf(fmaxf(v, -15.0f), 15.0f);
    float e = __expf(2.0f * v);
    return (e - 1.0f) * __builtin_amdgcn_rcpf(e + 1.0f);
}

__global__ __launch_bounds__(THREADS, 2) void wfc_kernel(
    const float* __restrict__ x, const int* __restrict__ nq,
    const int* __restrict__ lq, const int* __restrict__ mq,
    const float* __restrict__ W0, const float* __restrict__ b0,
    const float* __restrict__ W1, const float* __restrict__ b1,
    const float* __restrict__ Wa, const float* __restrict__ ba,
    const float* __restrict__ Wb, const float* __restrict__ bb,
    float* __restrict__ out)
{
    __shared__ float sW0[3 * 128];
    __shared__ float sb0[128];
    __shared__ float sW1t[64 * 132];   // [j][k], leading dim 132 (16B-aligned rows)
    __shared__ float sb1[64];

    const int tid = threadIdx.x;

    // ---- stage trunk weights ----
    for (int i = tid; i < 3 * 128; i += THREADS) sW0[i] = W0[i];
    if (tid < 128) sb0[tid] = b0[tid];
    if (tid < 64)  sb1[tid] = b1[tid];
    for (int i = tid; i < 128 * 64; i += THREADS) {
        int k = i >> 6, j = i & 63;           // W1 is (128,64) row-major
        sW1t[j * 132 + k] = W1[i];
    }
    __syncthreads();

    const int gid = blockIdx.x * THREADS + tid;

    // ---- load sample ----
    const float x0 = x[gid * 3 + 0];
    const float x1 = x[gid * 3 + 1];
    const float x2 = x[gid * 3 + 2];
    const int nn = nq[gid];
    const int ll = lq[gid];
    const int mm = mq[gid];
    // offset of expert block: sum_{i<n} i^2 = (n-1)n(2n-1)/6
    const int eid = ((nn - 1) * nn * (2 * nn - 1)) / 6 + ll * ll + ll + mm;

    // ---- layer 1: h1[128] in registers (fully unrolled => static indices) ----
    float h1[128];
    {
        const float4* w0r0 = (const float4*)(sW0);
        const float4* w0r1 = (const float4*)(sW0 + 128);
        const float4* w0r2 = (const float4*)(sW0 + 256);
        const float4* b0v  = (const float4*)(sb0);
#pragma unroll
        for (int kv = 0; kv < 32; ++kv) {
            float4 a = w0r0[kv], b = w0r1[kv], c = w0r2[kv], bv = b0v[kv];
            h1[4 * kv + 0] = fast_tanh(fmaf(x0, a.x, fmaf(x1, b.x, fmaf(x2, c.x, bv.x))));
            h1[4 * kv + 1] = fast_tanh(fmaf(x0, a.y, fmaf(x1, b.y, fmaf(x2, c.y, bv.y))));
            h1[4 * kv + 2] = fast_tanh(fmaf(x0, a.z, fmaf(x1, b.z, fmaf(x2, c.z, bv.z))));
            h1[4 * kv + 3] = fast_tanh(fmaf(x0, a.w, fmaf(x1, b.w, fmaf(x2, c.w, bv.w))));
        }
    }

    // ---- expert bias into g[32] ----
    float g[32];
    {
        const float4* bav = (const float4*)(ba + (eid << 5));
#pragma unroll
        for (int hv = 0; hv < 8; ++hv) {
            float4 b = bav[hv];
            g[4 * hv + 0] = b.x; g[4 * hv + 1] = b.y;
            g[4 * hv + 2] = b.z; g[4 * hv + 3] = b.w;
        }
    }

    // ---- fused layer2 + expert-A: for each d, h2[d] then accumulate into g ----
    const float4* wa = (const float4*)(Wa + (size_t)eid * 2048);
#pragma unroll 2
    for (int d = 0; d < 64; ++d) {
        const float4* wrow = (const float4*)(&sW1t[d * 132]);
        float a0 = 0.f, a1 = 0.f, a2 = 0.f, a3 = 0.f;
#pragma unroll
        for (int kv = 0; kv < 32; ++kv) {
            float4 w = wrow[kv];
            a0 = fmaf(h1[4 * kv + 0], w.x, a0);
            a1 = fmaf(h1[4 * kv + 1], w.y, a1);
            a2 = fmaf(h1[4 * kv + 2], w.z, a2);
            a3 = fmaf(h1[4 * kv + 3], w.w, a3);
        }
        const float hd = fast_tanh(sb1[d] + ((a0 + a1) + (a2 + a3)));
        const float4* wav = wa + d * 8;
#pragma unroll
        for (int hv = 0; hv < 8; ++hv) {
            float4 w = wav[hv];
            g[4 * hv + 0] = fmaf(hd, w.x, g[4 * hv + 0]);
            g[4 * hv + 1] = fmaf(hd, w.y, g[4 * hv + 1]);
            g[4 * hv + 2] = fmaf(hd, w.z, g[4 * hv + 2]);
            g[4 * hv + 3] = fmaf(hd, w.w, g[4 * hv + 3]);
        }
    }

    // ---- activation on g ----
#pragma unroll
    for (int h = 0; h < 32; ++h) g[h] = fast_tanh(g[h]);

    // ---- expert-B: psi = g . Wb[eid] + bb[eid] ----
    const float2 bbv = ((const float2*)bb)[eid];
    float p0 = bbv.x, p1 = bbv.y;
    {
        const float4* wbv = (const float4*)(Wb + (eid << 6));  // (32,2) row-major
#pragma unroll
        for (int hv = 0; hv < 16; ++hv) {
            float4 w = wbv[hv];      // covers h=2hv (x,y) and h=2hv+1 (z,w)
            p0 = fmaf(g[2 * hv + 0], w.x, p0);
            p1 = fmaf(g[2 * hv + 0], w.y, p1);
            p0 = fmaf(g[2 * hv + 1], w.z, p0);
            p1 = fmaf(g[2 * hv + 1], w.w, p1);
        }
    }

    // ---- normalize ----
    const float s = fmaf(p0, p0, fmaf(p1, p1, 1e-6f));
    const float inv = 1.0f / sqrtf(s);
    float2 o; o.x = p0 * inv; o.y = p1 * inv;
    ((float2*)out)[gid] = o;
}

extern "C" void kernel_launch(void* const* d_in, const int* in_sizes, int n_in,
                              void* d_out, int out_size, void* d_ws, size_t ws_size,
                              hipStream_t stream) {
    const float* x  = (const float*)d_in[0];
    const int*   n  = (const int*)d_in[1];
    const int*   l  = (const int*)d_in[2];
    const int*   m  = (const int*)d_in[3];
    const float* W0 = (const float*)d_in[4];
    const float* b0 = (const float*)d_in[5];
    const float* W1 = (const float*)d_in[6];
    const float* b1 = (const float*)d_in[7];
    const float* Wa = (const float*)d_in[8];
    const float* ba = (const float*)d_in[9];
    const float* Wb = (const float*)d_in[10];
    const float* bb = (const float*)d_in[11];
    float* out = (float*)d_out;

    const int B = in_sizes[1];          // 262144
    wfc_kernel<<<B / THREADS, THREADS, 0, stream>>>(
        x, n, l, m, W0, b0, W1, b1, Wa, ba, Wb, bb, out);
}